// Round 9
// baseline (476.605 us; speedup 1.0000x reference)
//
#include <hip/hip_runtime.h>
#include <hip/hip_fp16.h>

#define N_NODES 100000
#define N_EDGES 1600000
#define IN_CH 165
#define H1C 128
#define H2C 64
#define K1PAD 192                         // 6 k-steps of 32
#define CAP 64                            // fixed CSR capacity (Poisson(16): P(deg>=64)~1e-18)
#define SCATTER_BLOCKS 2048               // 8 partitions x 256 blocks
#define PART_SZ 12500                     // nodes per XCD partition (csr slice 3.2 MB < 4 MiB L2)
#define GEMM1_BLOCKS ((N_NODES + 63) / 64)  // 1563
#define NB128 ((N_NODES + 127) / 128)       // 782 blocks per channel-group

typedef _Float16 half8 __attribute__((ext_vector_type(8)));
typedef float floatx4 __attribute__((ext_vector_type(4)));
typedef int intx4 __attribute__((ext_vector_type(4)));   // NT-loadable int4

// ---------------- prep: zero cnt + convert/transpose weights to fp16 ----------------
__global__ __launch_bounds__(256) void prep(const float* __restrict__ W1,
                                            const float* __restrict__ W2,
                                            int* __restrict__ cnt,
                                            _Float16* __restrict__ w1t,
                                            _Float16* __restrict__ w2t) {
    int i = blockIdx.x * 256 + threadIdx.x;
    if (i < N_NODES) cnt[i] = 0;
    if (i < H1C * K1PAD) {                      // w1t[c][k], zero-padded k>=165
        int c = i / K1PAD, k = i - c * K1PAD;
        w1t[i] = (k < IN_CH) ? (_Float16)W1[k * H1C + c] : (_Float16)0.0f;
    }
    if (i < H2C * H1C) {                        // w2t[c][k]
        int c = i >> 7, k = i & 127;
        w2t[i] = (_Float16)W2[k * H2C + c];
    }
}

__global__ void dinv_from_cnt(const int* __restrict__ cnt, float* __restrict__ dinv) {
    int i = blockIdx.x * 256 + threadIdx.x;
    if (i < N_NODES) dinv[i] = rsqrtf((float)cnt[i] + 1.0f);
}

// ---------------- fused: XCD-partitioned fixed-CSR scatter ∥ gemm1 MFMA ----------------
// Scatter: int4-batched edge scan (4 edges/thread/iter); group g=blockIdx&7 owns
// dst range [g*PART_SZ,(g+1)*PART_SZ) so csr slab stays in its XCD's L2.
// gemm1: h1 = x*W1 via v_mfma_f32_16x16x32_f16, written CHANNEL-SLICED [8][N][16] fp16.
__global__ __launch_bounds__(256) void scatter_and_gemm1(
        const int* __restrict__ ei, int* __restrict__ cnt, int* __restrict__ csr,
        const float* __restrict__ x, const _Float16* __restrict__ w1t,
        _Float16* __restrict__ h1) {
    __shared__ _Float16 lsA[64 * 200];
    int tid = threadIdx.x;

    if (blockIdx.x < SCATTER_BLOCKS) {
        int g  = blockIdx.x & 7;          // partition == XCD (perf heuristic only)
        int bg = blockIdx.x >> 3;         // block within group [0,256)
        int lo = g * PART_SZ;
        int hi = lo + PART_SZ;            // 8*12500 == 100000 exactly
        const intx4* dst4 = (const intx4*)(ei + N_EDGES);
        const intx4* src4 = (const intx4*)ei;
        const int nchunks = N_EDGES / 4;  // 400000
        for (int i = bg * 256 + tid; i < nchunks; i += (SCATTER_BLOCKS / 8) * 256) {
            intx4 d = __builtin_nontemporal_load(&dst4[i]);
            bool m0 = (d.x >= lo) & (d.x < hi);
            bool m1 = (d.y >= lo) & (d.y < hi);
            bool m2 = (d.z >= lo) & (d.z < hi);
            bool m3 = (d.w >= lo) & (d.w < hi);
            if (m0 | m1 | m2 | m3) {
                intx4 s = __builtin_nontemporal_load(&src4[i]);
                if (m0) { int p = atomicAdd(&cnt[d.x], 1); if (p < CAP) csr[(d.x << 6) + p] = s.x; }
                if (m1) { int p = atomicAdd(&cnt[d.y], 1); if (p < CAP) csr[(d.y << 6) + p] = s.y; }
                if (m2) { int p = atomicAdd(&cnt[d.z], 1); if (p < CAP) csr[(d.z << 6) + p] = s.z; }
                if (m3) { int p = atomicAdd(&cnt[d.w], 1); if (p < CAP) csr[(d.w << 6) + p] = s.w; }
            }
        }
        return;
    }

    int bid = blockIdx.x - SCATTER_BLOCKS;
    int row0 = bid * 64;

    // stage A tile (fp32 -> fp16), coalesced non-temporal global read
    const int TILE_EL = 64 * IN_CH;  // 10560
    int base = row0 * IN_CH;
    for (int idx = tid; idx < TILE_EL; idx += 256) {
        int r = idx / IN_CH;
        int k = idx - r * IN_CH;
        int g = base + idx;
        float v = (g < N_NODES * IN_CH) ? __builtin_nontemporal_load(&x[g]) : 0.0f;
        lsA[r * 200 + k] = (_Float16)v;
    }
    // zero pad k in [165,200)
    for (int idx = tid; idx < 64 * 35; idx += 256) {
        int r = idx / 35;
        int k = IN_CH + (idx - r * 35);
        lsA[r * 200 + k] = (_Float16)0.0f;
    }
    __syncthreads();

    int lane = tid & 63;
    int w = tid >> 6;          // wave 0..3: N-strip of 32 cols
    int m = lane & 15;         // A row / B col / C col
    int q = lane >> 4;         // quad

    floatx4 acc[4][2] = {};
#pragma unroll
    for (int ks = 0; ks < 6; ++ks) {
        half8 af[4];
#pragma unroll
        for (int mt = 0; mt < 4; ++mt)
            af[mt] = *(const half8*)&lsA[(mt * 16 + m) * 200 + ks * 32 + q * 8];
        half8 bf[2];
#pragma unroll
        for (int nt = 0; nt < 2; ++nt)
            bf[nt] = *(const half8*)&w1t[((w * 2 + nt) * 16 + m) * K1PAD + ks * 32 + q * 8];
#pragma unroll
        for (int mt = 0; mt < 4; ++mt)
#pragma unroll
            for (int nt = 0; nt < 2; ++nt)
                acc[mt][nt] = __builtin_amdgcn_mfma_f32_16x16x32_f16(af[mt], bf[nt], acc[mt][nt], 0, 0, 0);
    }

    // epilogue: C/D layout col=lane&15, row=quad*4+reg. Channel-sliced store:
    // slice = col>>4 = w*2+nt, within-slice ch = m.
#pragma unroll
    for (int mt = 0; mt < 4; ++mt) {
#pragma unroll
        for (int nt = 0; nt < 2; ++nt) {
            _Float16* hs = h1 + (size_t)(w * 2 + nt) * N_NODES * 16;
#pragma unroll
            for (int reg = 0; reg < 4; ++reg) {
                int row = row0 + mt * 16 + q * 4 + reg;
                if (row < N_NODES) hs[(size_t)row * 16 + m] = (_Float16)acc[mt][nt][reg];
            }
        }
    }
}

// ---------------- agg layer1, channel-sliced: group g gathers its 16-ch slice ----------
// Grid: 8 groups x NB128 blocks; g = blockIdx&7 (XCD pin). Block covers 128 nodes.
// Wave = 8 sub-groups of 8 lanes; sub-group owns a node; lane owns 2 ch (half2).
__global__ __launch_bounds__(256) void agg1_sliced(const _Float16* __restrict__ h1,
                                                   const float* __restrict__ dinv,
                                                   const int* __restrict__ cnt,
                                                   const int* __restrict__ csr,
                                                   const float* __restrict__ b,
                                                   _Float16* __restrict__ a1) {
    int g  = blockIdx.x & 7;
    int nb = blockIdx.x >> 3;
    int tid = threadIdx.x;
    int wave = tid >> 6;
    int lane = tid & 63;
    int sub = lane >> 3;     // node slot in wave
    int cl  = lane & 7;      // half2 channel index within slice
    const __half2* hg = (const __half2*)(h1 + (size_t)g * N_NODES * 16);
    __half2* ag = (__half2*)(a1 + (size_t)g * N_NODES * 16);
    const float2* b2p = (const float2*)b;

#pragma unroll
    for (int rep = 0; rep < 4; ++rep) {
        int node = nb * 128 + rep * 32 + wave * 8 + sub;
        if (node >= N_NODES) break;
        int deg = min(cnt[node], CAP);
        const int* cp = csr + ((size_t)node << 6);
        const intx4* cp4 = (const intx4*)cp;
        float ax = 0.0f, ay = 0.0f;
        int e = 0;
        for (; e + 3 < deg; e += 4) {
            intx4 s = cp4[e >> 2];
            float n0 = dinv[s.x], n1 = dinv[s.y], n2 = dinv[s.z], n3 = dinv[s.w];
            float2 v0 = __half22float2(hg[(size_t)s.x * 8 + cl]);
            float2 v1 = __half22float2(hg[(size_t)s.y * 8 + cl]);
            float2 v2 = __half22float2(hg[(size_t)s.z * 8 + cl]);
            float2 v3 = __half22float2(hg[(size_t)s.w * 8 + cl]);
            ax += v0.x * n0 + v1.x * n1 + v2.x * n2 + v3.x * n3;
            ay += v0.y * n0 + v1.y * n1 + v2.y * n2 + v3.y * n3;
        }
        for (; e < deg; ++e) {
            int s0 = cp[e];
            float n0 = dinv[s0];
            float2 v0 = __half22float2(hg[(size_t)s0 * 8 + cl]);
            ax += v0.x * n0;
            ay += v0.y * n0;
        }
        float di = dinv[node];
        float2 hv = __half22float2(hg[(size_t)node * 8 + cl]);
        float2 bv = b2p[g * 8 + cl];
        float ox = fmaxf(ax * di + di * di * hv.x + bv.x, 0.0f);
        float oy = fmaxf(ay * di + di * di * hv.y + bv.y, 0.0f);
        ag[(size_t)node * 8 + cl] = __floats2half2_rn(ox, oy);
    }
}

// ---------------- gemm2 MFMA: a1 [8][N][16] fp16 * W2 -> h2 [4][N][16] fp16 ----------------
__global__ __launch_bounds__(256) void gemm2_mfma(const _Float16* __restrict__ A,
                                                  const _Float16* __restrict__ w2t,
                                                  _Float16* __restrict__ h2) {
    __shared__ _Float16 lsA[64 * 136];
    int tid = threadIdx.x;
    int row0 = blockIdx.x * 64;

    // stage 64x128 tile from sliced layout; per slice g: rows contiguous (32 B/row)
    const uint* a1u = (const uint*)A;  // half2 units
    for (int it = tid; it < 4096; it += 256) {
        int g = it >> 9;          // 512 half2 per slice-tile
        int rem = it & 511;
        int r = rem >> 3;
        int cl = rem & 7;
        int row = row0 + r;
        uint v = (row < N_NODES) ? a1u[(size_t)g * N_NODES * 8 + (size_t)row * 8 + cl] : 0u;
        *(uint*)&lsA[r * 136 + (g * 8 + cl) * 2] = v;
    }
    __syncthreads();

    int lane = tid & 63;
    int w = tid >> 6;          // wave = n-tile (16 cols) == output slice
    int m = lane & 15;
    int q = lane >> 4;

    floatx4 acc[4] = {};
#pragma unroll
    for (int ks = 0; ks < 4; ++ks) {
        half8 bf = *(const half8*)&w2t[(w * 16 + m) * H1C + ks * 32 + q * 8];
#pragma unroll
        for (int mt = 0; mt < 4; ++mt) {
            half8 af = *(const half8*)&lsA[(mt * 16 + m) * 136 + ks * 32 + q * 8];
            acc[mt] = __builtin_amdgcn_mfma_f32_16x16x32_f16(af, bf, acc[mt], 0, 0, 0);
        }
    }

    // col = w*16+m -> slice w, ch m
    _Float16* hs = h2 + (size_t)w * N_NODES * 16;
#pragma unroll
    for (int mt = 0; mt < 4; ++mt) {
#pragma unroll
        for (int reg = 0; reg < 4; ++reg) {
            int row = row0 + mt * 16 + q * 4 + reg;
            if (row < N_NODES) hs[(size_t)row * 16 + m] = (_Float16)acc[mt][reg];
        }
    }
}

// ---------------- agg layer2 channel-sliced + partial Wo projection ----------------
// 4 groups x NB128 blocks; per node: 16 ch -> relu -> partial (a0,a1) -> part[g][node]
__global__ __launch_bounds__(256) void agg2_sliced(const _Float16* __restrict__ h2,
                                                   const float* __restrict__ dinv,
                                                   const int* __restrict__ cnt,
                                                   const int* __restrict__ csr,
                                                   const float* __restrict__ b,
                                                   const float* __restrict__ Wo,
                                                   float2* __restrict__ part) {
    int g  = blockIdx.x & 3;
    int nb = blockIdx.x >> 2;
    int tid = threadIdx.x;
    int wave = tid >> 6;
    int lane = tid & 63;
    int sub = lane >> 3;
    int cl  = lane & 7;
    const __half2* hg = (const __half2*)(h2 + (size_t)g * N_NODES * 16);
    int c0 = g * 16 + cl * 2;  // global channel of .x

#pragma unroll
    for (int rep = 0; rep < 4; ++rep) {
        int node = nb * 128 + rep * 32 + wave * 8 + sub;
        if (node >= N_NODES) break;
        int deg = min(cnt[node], CAP);
        const int* cp = csr + ((size_t)node << 6);
        const intx4* cp4 = (const intx4*)cp;
        float ax = 0.0f, ay = 0.0f;
        int e = 0;
        for (; e + 3 < deg; e += 4) {
            intx4 s = cp4[e >> 2];
            float n0 = dinv[s.x], n1 = dinv[s.y], n2 = dinv[s.z], n3 = dinv[s.w];
            float2 v0 = __half22float2(hg[(size_t)s.x * 8 + cl]);
            float2 v1 = __half22float2(hg[(size_t)s.y * 8 + cl]);
            float2 v2 = __half22float2(hg[(size_t)s.z * 8 + cl]);
            float2 v3 = __half22float2(hg[(size_t)s.w * 8 + cl]);
            ax += v0.x * n0 + v1.x * n1 + v2.x * n2 + v3.x * n3;
            ay += v0.y * n0 + v1.y * n1 + v2.y * n2 + v3.y * n3;
        }
        for (; e < deg; ++e) {
            int s0 = cp[e];
            float n0 = dinv[s0];
            float2 v0 = __half22float2(hg[(size_t)s0 * 8 + cl]);
            ax += v0.x * n0;
            ay += v0.y * n0;
        }
        float di = dinv[node];
        float2 hv = __half22float2(hg[(size_t)node * 8 + cl]);
        float vx = fmaxf(ax * di + di * di * hv.x + b[c0], 0.0f);
        float vy = fmaxf(ay * di + di * di * hv.y + b[c0 + 1], 0.0f);
        float a0 = vx * Wo[c0 * 2] + vy * Wo[(c0 + 1) * 2];
        float a1 = vx * Wo[c0 * 2 + 1] + vy * Wo[(c0 + 1) * 2 + 1];
        // reduce over the 8 lanes of this sub-group (xor offsets stay in aligned 8-group)
#pragma unroll
        for (int off = 1; off < 8; off <<= 1) {
            a0 += __shfl_xor(a0, off, 64);
            a1 += __shfl_xor(a1, off, 64);
        }
        if (cl == 0) part[(size_t)g * N_NODES + node] = make_float2(a0, a1);
    }
}

// ---------------- final: out = sum_g part[g] + bo ----------------
__global__ void final_reduce(const float2* __restrict__ part, const float* __restrict__ bo,
                             float* __restrict__ out) {
    int i = blockIdx.x * 256 + threadIdx.x;
    if (i >= N_NODES) return;
    float2 p0 = part[i];
    float2 p1 = part[(size_t)N_NODES + i];
    float2 p2 = part[(size_t)2 * N_NODES + i];
    float2 p3 = part[(size_t)3 * N_NODES + i];
    float2 o = make_float2(p0.x + p1.x + p2.x + p3.x + bo[0],
                           p0.y + p1.y + p2.y + p3.y + bo[1]);
    *(float2*)&out[(size_t)i * 2] = o;
}

static inline char* align256(char* p) {
    return (char*)(((uintptr_t)p + 255) & ~(uintptr_t)255);
}

extern "C" void kernel_launch(void* const* d_in, const int* in_sizes, int n_in,
                              void* d_out, int out_size, void* d_ws, size_t ws_size,
                              hipStream_t stream) {
    const float* x  = (const float*)d_in[0];
    const int*   ei = (const int*)d_in[1];
    const float* W1 = (const float*)d_in[2];
    const float* b1 = (const float*)d_in[3];
    const float* W2 = (const float*)d_in[4];
    const float* b2 = (const float*)d_in[5];
    const float* Wo = (const float*)d_in[6];
    const float* bo = (const float*)d_in[7];
    float* out = (float*)d_out;

    // workspace layout (256B-aligned regions)
    char* wp = (char*)d_ws;
    int* cnt      = (int*)wp;        wp = align256(wp + sizeof(int) * N_NODES);
    int* csr      = (int*)wp;        wp = align256(wp + sizeof(int) * (size_t)N_NODES * CAP);
    float* dinv   = (float*)wp;      wp = align256(wp + sizeof(float) * N_NODES);
    _Float16* w1t = (_Float16*)wp;   wp = align256(wp + sizeof(_Float16) * H1C * K1PAD);
    _Float16* w2t = (_Float16*)wp;   wp = align256(wp + sizeof(_Float16) * H2C * H1C);
    _Float16* h1h = (_Float16*)wp;   wp = align256(wp + sizeof(_Float16) * (size_t)N_NODES * H1C);
    _Float16* a1h = (_Float16*)wp;   wp = align256(wp + sizeof(_Float16) * (size_t)N_NODES * H1C);
    _Float16* h2h = (_Float16*)wp;   wp = align256(wp + sizeof(_Float16) * (size_t)N_NODES * H2C);
    float2* part  = (float2*)wp;     wp = align256(wp + sizeof(float2) * (size_t)4 * N_NODES);

    const int nb_n = (N_NODES + 255) / 256;

    // prep (zero cnt + fp16 weights)
    prep<<<nb_n, 256, 0, stream>>>(W1, W2, cnt, w1t, w2t);

    // XCD-partitioned fixed-CSR scatter (int4-batched) ∥ gemm1 (sliced h1)
    scatter_and_gemm1<<<SCATTER_BLOCKS + GEMM1_BLOCKS, 256, 0, stream>>>(
        ei, cnt, csr, x, w1t, h1h);

    // dinv from final counts
    dinv_from_cnt<<<nb_n, 256, 0, stream>>>(cnt, dinv);

    // layer-1 aggregation, channel-sliced (8 groups)
    agg1_sliced<<<NB128 * 8, 256, 0, stream>>>(h1h, dinv, cnt, csr, b1, a1h);

    // layer 2 GEMM (sliced in, sliced out)
    gemm2_mfma<<<(N_NODES + 63) / 64, 256, 0, stream>>>(a1h, w2t, h2h);

    // layer-2 aggregation, channel-sliced (4 groups) + partial projection
    agg2_sliced<<<NB128 * 4, 256, 0, stream>>>(h2h, dinv, cnt, csr, b2, Wo, part);

    // final reduce
    final_reduce<<<nb_n, 256, 0, stream>>>(part, bo, out);
}

// Round 10
// 383.631 us; speedup vs baseline: 1.2424x; 1.2424x over previous
//
#include <hip/hip_runtime.h>
#include <hip/hip_fp16.h>

#define N_NODES 100000
#define N_EDGES 1600000
#define IN_CH 165
#define H1C 128
#define H2C 64
#define K1PAD 192                         // 6 k-steps of 32
#define CAP 64                            // fixed CSR capacity (Poisson(16): P(deg>=64)~1e-18)
#define SCATTER_BLOCKS 2048               // 8 partitions x 256 blocks
#define PART_SZ 12500                     // nodes per XCD partition (csr slice 3.2 MB < 4 MiB L2)
#define GEMM1_BLOCKS ((N_NODES + 63) / 64)  // 1563

typedef _Float16 half8 __attribute__((ext_vector_type(8)));
typedef float floatx4 __attribute__((ext_vector_type(4)));
typedef int intx4 __attribute__((ext_vector_type(4)));   // NT/vector-loadable int4

// ---------------- prep: zero cnt + convert/transpose weights to fp16 ----------------
__global__ __launch_bounds__(256) void prep(const float* __restrict__ W1,
                                            const float* __restrict__ W2,
                                            int* __restrict__ cnt,
                                            _Float16* __restrict__ w1t,
                                            _Float16* __restrict__ w2t) {
    int i = blockIdx.x * 256 + threadIdx.x;
    if (i < N_NODES) cnt[i] = 0;
    if (i < H1C * K1PAD) {                      // w1t[c][k], zero-padded k>=165
        int c = i / K1PAD, k = i - c * K1PAD;
        w1t[i] = (k < IN_CH) ? (_Float16)W1[k * H1C + c] : (_Float16)0.0f;
    }
    if (i < H2C * H1C) {                        // w2t[c][k]
        int c = i >> 7, k = i & 127;
        w2t[i] = (_Float16)W2[k * H2C + c];
    }
}

// ---------------- fused: XCD-partitioned fixed-CSR scatter ∥ gemm1 MFMA ----------------
// Scatter: int4-batched NT edge scan; group g=blockIdx&7 owns dst range
// [g*PART_SZ,(g+1)*PART_SZ) so its csr slab stays in one XCD's L2.
// gemm1: h1[N,128] fp16 = x[N,165]*W1 via v_mfma_f32_16x16x32_f16 (row-major h1).
__global__ __launch_bounds__(256) void scatter_and_gemm1(
        const int* __restrict__ ei, int* __restrict__ cnt, int* __restrict__ csr,
        const float* __restrict__ x, const _Float16* __restrict__ w1t,
        _Float16* __restrict__ h1) {
    __shared__ _Float16 lsA[64 * 200];
    int tid = threadIdx.x;

    if (blockIdx.x < SCATTER_BLOCKS) {
        int g  = blockIdx.x & 7;          // partition == XCD (perf heuristic only)
        int bg = blockIdx.x >> 3;         // block within group [0,256)
        int lo = g * PART_SZ;
        int hi = lo + PART_SZ;            // 8*12500 == 100000 exactly
        const intx4* dst4 = (const intx4*)(ei + N_EDGES);
        const intx4* src4 = (const intx4*)ei;
        const int nchunks = N_EDGES / 4;  // 400000
        for (int i = bg * 256 + tid; i < nchunks; i += (SCATTER_BLOCKS / 8) * 256) {
            intx4 d = __builtin_nontemporal_load(&dst4[i]);
            bool m0 = (d.x >= lo) & (d.x < hi);
            bool m1 = (d.y >= lo) & (d.y < hi);
            bool m2 = (d.z >= lo) & (d.z < hi);
            bool m3 = (d.w >= lo) & (d.w < hi);
            if (m0 | m1 | m2 | m3) {
                intx4 s = __builtin_nontemporal_load(&src4[i]);
                if (m0) { int p = atomicAdd(&cnt[d.x], 1); if (p < CAP) csr[(d.x << 6) + p] = s.x; }
                if (m1) { int p = atomicAdd(&cnt[d.y], 1); if (p < CAP) csr[(d.y << 6) + p] = s.y; }
                if (m2) { int p = atomicAdd(&cnt[d.z], 1); if (p < CAP) csr[(d.z << 6) + p] = s.z; }
                if (m3) { int p = atomicAdd(&cnt[d.w], 1); if (p < CAP) csr[(d.w << 6) + p] = s.w; }
            }
        }
        return;
    }

    int bid = blockIdx.x - SCATTER_BLOCKS;
    int row0 = bid * 64;

    // stage A tile (fp32 -> fp16), coalesced non-temporal global read
    const int TILE_EL = 64 * IN_CH;  // 10560
    int base = row0 * IN_CH;
    for (int idx = tid; idx < TILE_EL; idx += 256) {
        int r = idx / IN_CH;
        int k = idx - r * IN_CH;
        int g = base + idx;
        float v = (g < N_NODES * IN_CH) ? __builtin_nontemporal_load(&x[g]) : 0.0f;
        lsA[r * 200 + k] = (_Float16)v;
    }
    // zero pad k in [165,200)
    for (int idx = tid; idx < 64 * 35; idx += 256) {
        int r = idx / 35;
        int k = IN_CH + (idx - r * 35);
        lsA[r * 200 + k] = (_Float16)0.0f;
    }
    __syncthreads();

    int lane = tid & 63;
    int w = tid >> 6;          // wave 0..3: N-strip of 32 cols
    int m = lane & 15;         // A row / B col / C col
    int q = lane >> 4;         // quad

    floatx4 acc[4][2] = {};
#pragma unroll
    for (int ks = 0; ks < 6; ++ks) {
        half8 af[4];
#pragma unroll
        for (int mt = 0; mt < 4; ++mt)
            af[mt] = *(const half8*)&lsA[(mt * 16 + m) * 200 + ks * 32 + q * 8];
        half8 bf[2];
#pragma unroll
        for (int nt = 0; nt < 2; ++nt)
            bf[nt] = *(const half8*)&w1t[((w * 2 + nt) * 16 + m) * K1PAD + ks * 32 + q * 8];
#pragma unroll
        for (int mt = 0; mt < 4; ++mt)
#pragma unroll
            for (int nt = 0; nt < 2; ++nt)
                acc[mt][nt] = __builtin_amdgcn_mfma_f32_16x16x32_f16(af[mt], bf[nt], acc[mt][nt], 0, 0, 0);
    }

    // epilogue: C/D layout col=lane&15, row=quad*4+reg (regular stores, not NT)
#pragma unroll
    for (int mt = 0; mt < 4; ++mt) {
#pragma unroll
        for (int nt = 0; nt < 2; ++nt) {
            int col = (w * 2 + nt) * 16 + m;
#pragma unroll
            for (int reg = 0; reg < 4; ++reg) {
                int row = row0 + mt * 16 + q * 4 + reg;
                if (row < N_NODES) h1[(size_t)row * H1C + col] = (_Float16)acc[mt][nt][reg];
            }
        }
    }
}

// ---------------- agg layer1: wave-per-node gather (+self-loop+bias+relu) ----------------
// Row-major h1 [N][128] fp16: wave reads full 256B rows, fully coalesced.
// dinv computed inline from cnt (no separate dinv array/kernel).
__global__ __launch_bounds__(256) void agg_gather_128(const __half* __restrict__ h,
                                                      const int* __restrict__ cnt,
                                                      const int* __restrict__ csr,
                                                      const float* __restrict__ b,
                                                      __half* __restrict__ out) {
    const __half2* hp = (const __half2*)h;  // [N, 64] half2
    int wave = threadIdx.x >> 6;
    int lane = threadIdx.x & 63;
    int node = blockIdx.x * 4 + wave;
    if (node >= N_NODES) return;
    int c = cnt[node];
    int deg = min(c, CAP);
    float di = rsqrtf((float)c + 1.0f);
    const intx4* cp4 = (const intx4*)(csr + ((size_t)node << 6));
    const int* cp = (const int*)cp4;
    float ax = 0.0f, ay = 0.0f;
    int e = 0;
    for (; e + 3 < deg; e += 4) {
        intx4 s = cp4[e >> 2];
        float n0 = rsqrtf((float)cnt[s.x] + 1.0f);
        float n1 = rsqrtf((float)cnt[s.y] + 1.0f);
        float n2 = rsqrtf((float)cnt[s.z] + 1.0f);
        float n3 = rsqrtf((float)cnt[s.w] + 1.0f);
        float2 v0 = __half22float2(hp[(size_t)s.x * 64 + lane]);
        float2 v1 = __half22float2(hp[(size_t)s.y * 64 + lane]);
        float2 v2 = __half22float2(hp[(size_t)s.z * 64 + lane]);
        float2 v3 = __half22float2(hp[(size_t)s.w * 64 + lane]);
        ax += v0.x * n0 + v1.x * n1 + v2.x * n2 + v3.x * n3;
        ay += v0.y * n0 + v1.y * n1 + v2.y * n2 + v3.y * n3;
    }
    for (; e < deg; ++e) {
        int s0 = cp[e];
        float n0 = rsqrtf((float)cnt[s0] + 1.0f);
        float2 v0 = __half22float2(hp[(size_t)s0 * 64 + lane]);
        ax += v0.x * n0;
        ay += v0.y * n0;
    }
    float2 hv = __half22float2(hp[(size_t)node * 64 + lane]);
    float2 bv = *(const float2*)&b[lane * 2];
    float ox = fmaxf(ax * di + di * di * hv.x + bv.x, 0.0f);
    float oy = fmaxf(ay * di + di * di * hv.y + bv.y, 0.0f);
    ((__half2*)out)[(size_t)node * 64 + lane] = __floats2half2_rn(ox, oy);
}

// ---------------- gemm2 MFMA: a1[N,128] fp16 * W2 -> h2[N,64] fp16 ----------------
__global__ __launch_bounds__(256) void gemm2_mfma(const _Float16* __restrict__ A,
                                                  const _Float16* __restrict__ w2t,
                                                  _Float16* __restrict__ h2) {
    __shared__ _Float16 lsA[64 * 136];
    int tid = threadIdx.x;
    int row0 = blockIdx.x * 64;

    const uint* srcu = (const uint*)(A + (size_t)row0 * H1C);
    for (int idx = tid; idx < 4096; idx += 256) {
        int r = idx >> 6;
        int kp = idx & 63;
        uint v = ((size_t)(row0 + r) < (size_t)N_NODES) ? srcu[idx] : 0u;
        *(uint*)&lsA[r * 136 + kp * 2] = v;
    }
    __syncthreads();

    int lane = tid & 63;
    int w = tid >> 6;          // wave = n-tile (16 cols)
    int m = lane & 15;
    int q = lane >> 4;

    floatx4 acc[4] = {};
#pragma unroll
    for (int ks = 0; ks < 4; ++ks) {
        half8 bf = *(const half8*)&w2t[(w * 16 + m) * H1C + ks * 32 + q * 8];
#pragma unroll
        for (int mt = 0; mt < 4; ++mt) {
            half8 af = *(const half8*)&lsA[(mt * 16 + m) * 136 + ks * 32 + q * 8];
            acc[mt] = __builtin_amdgcn_mfma_f32_16x16x32_f16(af, bf, acc[mt], 0, 0, 0);
        }
    }

    int col = w * 16 + m;
#pragma unroll
    for (int mt = 0; mt < 4; ++mt) {
#pragma unroll
        for (int reg = 0; reg < 4; ++reg) {
            int row = row0 + mt * 16 + q * 4 + reg;
            if (row < N_NODES) h2[(size_t)row * H2C + col] = (_Float16)acc[mt][reg];
        }
    }
}

// ---------------- agg layer2 + final projection fused ----------------
__global__ __launch_bounds__(256) void agg_gather_64_final(const __half* __restrict__ h,
                                                           const int* __restrict__ cnt,
                                                           const int* __restrict__ csr,
                                                           const float* __restrict__ b,
                                                           const float* __restrict__ Wo,
                                                           const float* __restrict__ bo,
                                                           float* __restrict__ out) {
    int wave = threadIdx.x >> 6;
    int lane = threadIdx.x & 63;
    int node = blockIdx.x * 4 + wave;
    if (node >= N_NODES) return;
    int c = cnt[node];
    int deg = min(c, CAP);
    float di = rsqrtf((float)c + 1.0f);
    const intx4* cp4 = (const intx4*)(csr + ((size_t)node << 6));
    const int* cp = (const int*)cp4;
    float acc = 0.0f;
    int e = 0;
    for (; e + 3 < deg; e += 4) {
        intx4 s = cp4[e >> 2];
        float n0 = rsqrtf((float)cnt[s.x] + 1.0f);
        float n1 = rsqrtf((float)cnt[s.y] + 1.0f);
        float n2 = rsqrtf((float)cnt[s.z] + 1.0f);
        float n3 = rsqrtf((float)cnt[s.w] + 1.0f);
        float v0 = __half2float(h[(size_t)s.x * H2C + lane]);
        float v1 = __half2float(h[(size_t)s.y * H2C + lane]);
        float v2 = __half2float(h[(size_t)s.z * H2C + lane]);
        float v3 = __half2float(h[(size_t)s.w * H2C + lane]);
        acc += v0 * n0 + v1 * n1 + v2 * n2 + v3 * n3;
    }
    for (; e < deg; ++e) {
        int s0 = cp[e];
        acc += __half2float(h[(size_t)s0 * H2C + lane]) * rsqrtf((float)cnt[s0] + 1.0f);
    }
    float hv = __half2float(h[(size_t)node * H2C + lane]);
    float v = fmaxf(acc * di + di * di * hv + b[lane], 0.0f);
    float a0 = v * Wo[lane * 2];
    float a1 = v * Wo[lane * 2 + 1];
#pragma unroll
    for (int off = 32; off > 0; off >>= 1) {
        a0 += __shfl_down(a0, off, 64);
        a1 += __shfl_down(a1, off, 64);
    }
    if (lane == 0) {
        *(float2*)&out[(size_t)node * 2] = make_float2(a0 + bo[0], a1 + bo[1]);
    }
}

static inline char* align256(char* p) {
    return (char*)(((uintptr_t)p + 255) & ~(uintptr_t)255);
}

extern "C" void kernel_launch(void* const* d_in, const int* in_sizes, int n_in,
                              void* d_out, int out_size, void* d_ws, size_t ws_size,
                              hipStream_t stream) {
    const float* x  = (const float*)d_in[0];
    const int*   ei = (const int*)d_in[1];
    const float* W1 = (const float*)d_in[2];
    const float* b1 = (const float*)d_in[3];
    const float* W2 = (const float*)d_in[4];
    const float* b2 = (const float*)d_in[5];
    const float* Wo = (const float*)d_in[6];
    const float* bo = (const float*)d_in[7];
    float* out = (float*)d_out;

    // workspace layout (256B-aligned regions)
    char* wp = (char*)d_ws;
    int* cnt      = (int*)wp;        wp = align256(wp + sizeof(int) * N_NODES);
    int* csr      = (int*)wp;        wp = align256(wp + sizeof(int) * (size_t)N_NODES * CAP);
    _Float16* w1t = (_Float16*)wp;   wp = align256(wp + sizeof(_Float16) * H1C * K1PAD);
    _Float16* w2t = (_Float16*)wp;   wp = align256(wp + sizeof(_Float16) * H2C * H1C);
    _Float16* h1h = (_Float16*)wp;   wp = align256(wp + sizeof(_Float16) * (size_t)N_NODES * H1C);
    _Float16* a1h = (_Float16*)wp;   wp = align256(wp + sizeof(_Float16) * (size_t)N_NODES * H1C);
    _Float16* h2h = (_Float16*)wp;   wp = align256(wp + sizeof(_Float16) * (size_t)N_NODES * H2C);

    const int nb_n   = (N_NODES + 255) / 256;
    const int nb_nd4 = (N_NODES + 3) / 4;

    // prep (zero cnt + fp16 weights)
    prep<<<nb_n, 256, 0, stream>>>(W1, W2, cnt, w1t, w2t);

    // XCD-partitioned fixed-CSR scatter (int4 NT scan) ∥ gemm1
    scatter_and_gemm1<<<SCATTER_BLOCKS + GEMM1_BLOCKS, 256, 0, stream>>>(
        ei, cnt, csr, x, w1t, h1h);

    // layer-1 aggregation (fp16 out), dinv inline
    agg_gather_128<<<nb_nd4, 256, 0, stream>>>((const __half*)h1h, cnt, csr, b1,
                                               (__half*)a1h);

    // layer 2 GEMM
    gemm2_mfma<<<(N_NODES + 63) / 64, 256, 0, stream>>>(a1h, w2t, h2h);

    // layer-2 aggregation + final projection
    agg_gather_64_final<<<nb_nd4, 256, 0, stream>>>((const __half*)h2h, cnt, csr,
                                                    b2, Wo, bo, out);
}